// Round 14
// baseline (1578.633 us; speedup 1.0000x reference)
//
#include <hip/hip_runtime.h>
#include <math.h>

// Problem constants (GATModel: N=50000, E=800000, F_IN=128, HID=OUT=64, H=4)
constexpr int NNODE = 50000;
constexpr int FIN   = 128;
constexpr int HID   = 64;
constexpr int NH    = 4;
constexpr int NC    = 256;   // NH * HID
constexpr float NEG = 0.2f;
constexpr int MPAD  = 50048; // NNODE padded to 64-row tiles (782*64)
constexpr int SCANB = (NNODE + 255) / 256;  // 196
constexpr int NODEB = (NNODE + 3) / 4;      // 12500 agg blocks (4 nodes each)
constexpr int GEMMB = MPAD / 64;            // 782 gemm tiles/blocks

typedef unsigned short u16;
typedef short bf16x8 __attribute__((ext_vector_type(8)));
typedef float f32x4 __attribute__((ext_vector_type(4)));

__device__ __forceinline__ u16 f2bf(float f) {  // round-to-nearest-even
  unsigned int u = __float_as_uint(f);
  return (u16)((u + 0x7FFF + ((u >> 16) & 1)) >> 16);
}
__device__ __forceinline__ float bf2f(u16 h) {
  return __uint_as_float(((unsigned int)h) << 16);
}
__device__ __forceinline__ float readlane_f(float v, int l) {
  return __int_as_float(__builtin_amdgcn_readlane(__float_as_int(v), l));
}

// ---------------- fused: count_deg + weight packing (independent work) ----------------
__global__ __launch_bounds__(256) void count_pack(const int* __restrict__ ei, int* __restrict__ deg,
                                                  int* __restrict__ rank, int E, int edgeBlocks,
                                                  const float* __restrict__ W1, const float* __restrict__ W2,
                                                  u16* __restrict__ Bp1, u16* __restrict__ Bp2) {
  int b = blockIdx.x;
  if (b < edgeBlocks) {
    int i = b * 256 + threadIdx.x;
    if (i < E) rank[i] = atomicAdd(&deg[ei[E + i]], 1);
  } else {
    int i = (b - edgeBlocks) * 256 + threadIdx.x;
    const int t1 = FIN * NC;
    const int t2 = HID * NC;
    if (i < t1) {
      int k = i >> 8, c = i & 255;
      Bp1[((size_t)(k >> 3) * 256 + c) * 8 + (k & 7)] = f2bf(W1[i]);
    } else if (i < t1 + t2) {
      int j = i - t1;
      int k = j >> 8, c = j & 255;
      Bp2[((size_t)(k >> 3) * 256 + c) * 8 + (k & 7)] = f2bf(W2[j]);
    }
  }
}

// ---------------- scan phase 1: per-block degree sums ----------------
__global__ __launch_bounds__(256) void scan_phase1(const int* __restrict__ deg,
                                                   int* __restrict__ blockSums, int n) {
  __shared__ int sm[256];
  int tid = threadIdx.x;
  int i = blockIdx.x * 256 + tid;
  sm[tid] = (i < n) ? deg[i] : 0;
  __syncthreads();
#pragma unroll
  for (int o = 128; o > 0; o >>= 1) {
    if (tid < o) sm[tid] += sm[tid + o];
    __syncthreads();
  }
  if (tid == 0) blockSums[blockIdx.x] = sm[0];
}

// ---------------- scan phases 2+3 fused ----------------
__global__ __launch_bounds__(256) void scan_phase23(const int* __restrict__ blockSums,
                                                    const int* __restrict__ deg,
                                                    int* __restrict__ offs, int n) {
  __shared__ int ss[256];
  __shared__ int sm[256];
  int tid = threadIdx.x;
  ss[tid] = (tid < SCANB) ? blockSums[tid] : 0;
  __syncthreads();
#pragma unroll
  for (int o = 1; o < 256; o <<= 1) {
    int t = (tid >= o) ? ss[tid - o] : 0;
    __syncthreads();
    ss[tid] += t;
    __syncthreads();
  }
  int blockOff = (blockIdx.x == 0) ? 0 : ss[blockIdx.x - 1];
  int i = blockIdx.x * 256 + tid;
  int v = (i < n) ? deg[i] : 0;
  sm[tid] = v;
  __syncthreads();
#pragma unroll
  for (int o = 1; o < 256; o <<= 1) {
    int t = (tid >= o) ? sm[tid - o] : 0;
    __syncthreads();
    sm[tid] += t;
    __syncthreads();
  }
  int ex = sm[tid] - v + blockOff;
  if (i < n) offs[i] = ex;
  if (blockIdx.x == SCANB - 1 && tid == 255) offs[n] = ss[SCANB - 1];  // offs[N] = E
}

// ---------------- MFMA bf16 GEMM body ----------------
// A-frag: lane holds A[m = lane&15][k = (lane>>4)*8 + j]
// B-frag: lane holds B[k = (lane>>4)*8 + j][n = lane&15]  (packed Bp)
// D: col = lane&15, row = (lane>>4)*4 + reg   [m89/m91-verified layouts]
template <int KS, bool AF32>  // K = 32*KS
__device__ __forceinline__ void gemm_body(
    int bx, const void* __restrict__ Aptr, const u16* __restrict__ Bp,
    const float* __restrict__ a_s, const float* __restrict__ a_d,
    u16* __restrict__ hf16, float* __restrict__ al_s, float* __restrict__ al_d, int M) {
  const int K = 32 * KS;
  int lane = threadIdx.x & 63;
  int wv = threadIdx.x >> 6;
  int q = lane >> 4, r = lane & 15;
  int m0 = bx * 64 + wv * 16;

  bf16x8 af[KS];
  if (AF32) {
    int ar = m0 + r; if (ar >= M) ar = M - 1;   // clamp (stores guarded)
    const float* arow = (const float*)Aptr + (size_t)ar * K + q * 8;
#pragma unroll
    for (int ks = 0; ks < KS; ++ks) {
      float4 v0 = *(const float4*)(arow + ks * 32);
      float4 v1 = *(const float4*)(arow + ks * 32 + 4);
      bf16x8 t;
      t[0] = (short)f2bf(v0.x); t[1] = (short)f2bf(v0.y);
      t[2] = (short)f2bf(v0.z); t[3] = (short)f2bf(v0.w);
      t[4] = (short)f2bf(v1.x); t[5] = (short)f2bf(v1.y);
      t[6] = (short)f2bf(v1.z); t[7] = (short)f2bf(v1.w);
      af[ks] = t;
    }
  } else {
    const u16* arow = (const u16*)Aptr + (size_t)(m0 + r) * K + q * 8;  // padded buffer
#pragma unroll
    for (int ks = 0; ks < KS; ++ks) af[ks] = *(const bf16x8*)(arow + ks * 32);
  }

  int node_base = m0 + q * 4;
#pragma unroll
  for (int h = 0; h < NH; ++h) {
    f32x4 acc[4];
#pragma unroll
    for (int c4 = 0; c4 < 4; ++c4) {
      acc[c4] = (f32x4){0.f, 0.f, 0.f, 0.f};
      const u16* bp = Bp + ((size_t)q * 256 + (h * 4 + c4) * 16 + r) * 8;
#pragma unroll
      for (int ks = 0; ks < KS; ++ks) {
        bf16x8 bf = *(const bf16x8*)(bp + (size_t)ks * 4 * 256 * 8);
        acc[c4] = __builtin_amdgcn_mfma_f32_16x16x32_bf16(af[ks], bf, acc[c4], 0, 0, 0);
      }
    }
    float ps[4] = {0.f, 0.f, 0.f, 0.f}, pd[4] = {0.f, 0.f, 0.f, 0.f};
#pragma unroll
    for (int c4 = 0; c4 < 4; ++c4) {
      float sa = a_s[h * HID + c4 * 16 + r];
      float da = a_d[h * HID + c4 * 16 + r];
#pragma unroll
      for (int reg = 0; reg < 4; ++reg) {
        float v = acc[c4][reg];
        ps[reg] += v * sa;
        pd[reg] += v * da;
        int node = node_base + reg;
        if (node < M) hf16[(size_t)node * NC + (c4 * 16 + r) * NH + h] = f2bf(v);
      }
    }
#pragma unroll
    for (int reg = 0; reg < 4; ++reg) {
#pragma unroll
      for (int o = 1; o < 16; o <<= 1) {
        ps[reg] += __shfl_xor(ps[reg], o);
        pd[reg] += __shfl_xor(pd[reg], o);
      }
      int node = node_base + reg;
      if (r == 0 && node < M) {
        al_s[node * NH + h] = ps[reg];
        al_d[node * NH + h] = pd[reg];
      }
    }
  }
}

// ---------------- fused: gemm layer-1 + atomic-free edge scatter ----------------
__global__ __launch_bounds__(256) void gemm1_scatter(
    const float* __restrict__ x, const u16* __restrict__ Bp1,
    const float* __restrict__ a_s, const float* __restrict__ a_d,
    u16* __restrict__ hf16, float* __restrict__ al_s, float* __restrict__ al_d, int M,
    const int* __restrict__ ei, const int* __restrict__ offs, const int* __restrict__ rank,
    int* __restrict__ csr_src, int E, int gemmBlocks) {
  int b = blockIdx.x;
  if (b < gemmBlocks) {
    gemm_body<4, true>(b, x, Bp1, a_s, a_d, hf16, al_s, al_d, M);
  } else {
    int i = (b - gemmBlocks) * 256 + threadIdx.x;
    if (i < E) {
      int dst = ei[E + i];
      csr_src[offs[dst] + rank[i]] = ei[i];   // no atomic (rank from count_pack)
    }
  }
}

// ---------------- aggregation body (per node, one wave) ----------------
// Mask-padded chunks of 8, depth-1 pipeline on gathers, denom via shfl tree.
// No max-shift: logits bounded ~|e|<20 => exp(e)/sum identical to reference's
// shifted softmax.
template <bool FINAL>
__device__ __forceinline__ void agg_body(int node,
                                         const u16* __restrict__ hf16,
                                         const float4* __restrict__ al_s4,
                                         const float4* __restrict__ al_d4,
                                         const int* __restrict__ offs, const int* __restrict__ csr_src,
                                         const float* __restrict__ bias, void* __restrict__ out_v) {
  int lane = threadIdx.x & 63;
  float4 ad = al_d4[node];
  int lj = lane & 7;
  int hsel = (lane >> 3) & 3;
  float adv = hsel == 0 ? ad.x : (hsel == 1 ? ad.y : (hsel == 2 ? ad.z : ad.w));
  float c0 = 0.f, c1 = 0.f, c2 = 0.f, c3 = 0.f;
  float dacc = 0.f;
  int s = offs[node], e = offs[node + 1];
  int nch = (e - s + 7) >> 3;
  int i = s;

  int vidx = 0;
  float4 as = make_float4(0.f, 0.f, 0.f, 0.f);
  ushort4 hv[8];
  if (nch > 0) {
    int id0 = i + lj; if (id0 >= e) id0 = e - 1;
    vidx = csr_src[id0];
    as = al_s4[vidx];
#pragma unroll
    for (int j = 0; j < 8; ++j) {
      int sa = __builtin_amdgcn_readlane(vidx, j);
      hv[j] = ((const ushort4*)(hf16 + (size_t)sa * NC))[lane];
    }
  }

  for (int ch = 0; ch < nch; ++ch) {
    bool last = (ch + 1 == nch);
    float asv = hsel == 0 ? as.x : (hsel == 1 ? as.y : (hsel == 2 ? as.z : as.w));
    float ev = asv + adv;
    ev = ev >= 0.f ? ev : NEG * ev;
    float wv = __expf(ev);
    if (i + lj >= e) wv = 0.f;
    float t = wv;
    t += __shfl_xor(t, 1); t += __shfl_xor(t, 2); t += __shfl_xor(t, 4);
    dacc += t;
    int vidx_n = 0;
    float4 as_n = make_float4(0.f, 0.f, 0.f, 0.f);
    ushort4 hn[8];
    if (!last) {
      int id1 = i + 8 + lj; if (id1 >= e) id1 = e - 1;
      vidx_n = csr_src[id1];
      as_n = al_s4[vidx_n];
#pragma unroll
      for (int j = 0; j < 8; ++j) {
        int sa = __builtin_amdgcn_readlane(vidx_n, j);
        hn[j] = ((const ushort4*)(hf16 + (size_t)sa * NC))[lane];
      }
    }
#pragma unroll
    for (int j = 0; j < 8; ++j) {
      float wx = readlane_f(wv, j);
      float wy = readlane_f(wv, 8 + j);
      float wz = readlane_f(wv, 16 + j);
      float ww = readlane_f(wv, 24 + j);
      c0 += wx * bf2f(hv[j].x);
      c1 += wy * bf2f(hv[j].y);
      c2 += wz * bf2f(hv[j].z);
      c3 += ww * bf2f(hv[j].w);
    }
    if (!last) {
      vidx = vidx_n; as = as_n;
#pragma unroll
      for (int j = 0; j < 8; ++j) hv[j] = hn[j];
    }
    i += 8;
  }
  float d0 = readlane_f(dacc, 0), d1 = readlane_f(dacc, 8);
  float d2 = readlane_f(dacc, 16), d3 = readlane_f(dacc, 24);
  float val = 0.25f * (c0 / (d0 + 1e-16f) + c1 / (d1 + 1e-16f) +
                       c2 / (d2 + 1e-16f) + c3 / (d3 + 1e-16f)) + bias[lane];
  if (!FINAL) {
    ((u16*)out_v)[(size_t)node * HID + lane] = f2bf(fmaxf(val, 0.f));
  } else {
    float mx = val;
#pragma unroll
    for (int o = 32; o >= 1; o >>= 1) mx = fmaxf(mx, __shfl_xor(mx, o));
    float ex = __expf(val - mx);
    float sm = ex;
#pragma unroll
    for (int o = 32; o >= 1; o >>= 1) sm += __shfl_xor(sm, o);
    ((float*)out_v)[(size_t)node * HID + lane] = (val - mx) - logf(sm);
  }
}

// ---------------- fused: agg layer-1 + gemm layer-2 (readiness counters) ----------------
// Blocks [0,NODEB): agg<false> on 4 nodes -> h1bf rows; then threadfence +
// atomicAdd(ready[tile]) (tile = 64 nodes = 16 agg blocks). Blocks
// [NODEB,NODEB+GEMMB): spin until their tile's counter is full, then run the
// layer-2 GEMM on those rows. Deadlock-free: agg blocks never wait; at most
// 782 spinners < resident-slot count. gemm2 writes go to SEPARATE buffers
// (hf16b/al2) so agg1's layer-1 reads are never clobbered.
__global__ __launch_bounds__(256) void agg1_gemm2(
    const u16* __restrict__ hf16a, const float4* __restrict__ al_s1, const float4* __restrict__ al_d1,
    const int* __restrict__ offs, const int* __restrict__ csr_src,
    const float* __restrict__ b1, u16* __restrict__ h1bf, int n,
    int* __restrict__ ready,
    const u16* __restrict__ Bp2, const float* __restrict__ as2, const float* __restrict__ ad2,
    u16* __restrict__ hf16b, float* __restrict__ al_s2, float* __restrict__ al_d2, int M) {
  int b = blockIdx.x;
  if (b < NODEB) {
    int node = b * 4 + (threadIdx.x >> 6);
    if (node < n) agg_body<false>(node, hf16a, al_s1, al_d1, offs, csr_src, b1, h1bf);
    __threadfence();       // each thread flushes its h1bf stores to device scope
    __syncthreads();
    if (threadIdx.x == 0) atomicAdd(&ready[b >> 4], 1);
  } else {
    int tile = b - NODEB;
    if (threadIdx.x == 0) {
      int exp_cnt = min(16, NODEB - 16 * tile);
      while (__hip_atomic_load(&ready[tile], __ATOMIC_ACQUIRE, __HIP_MEMORY_SCOPE_AGENT) < exp_cnt)
        __builtin_amdgcn_s_sleep(8);
      __threadfence();
    }
    __syncthreads();
    gemm_body<2, false>(tile, h1bf, Bp2, as2, ad2, hf16b, al_s2, al_d2, M);
  }
}

// ---------------- layer-2 aggregation (standalone) ----------------
__global__ __launch_bounds__(256) void agg2_kernel(const u16* __restrict__ hf16,
                                                   const float4* __restrict__ al_s4,
                                                   const float4* __restrict__ al_d4,
                                                   const int* __restrict__ offs, const int* __restrict__ csr_src,
                                                   const float* __restrict__ bias, float* __restrict__ out, int n) {
  int node = blockIdx.x * 4 + (threadIdx.x >> 6);
  if (node >= n) return;
  agg_body<true>(node, hf16, al_s4, al_d4, offs, csr_src, bias, out);
}

// ---------------- launch ----------------
extern "C" void kernel_launch(void* const* d_in, const int* in_sizes, int n_in,
                              void* d_out, int out_size, void* d_ws, size_t ws_size,
                              hipStream_t stream) {
  const float* x   = (const float*)d_in[0];
  const int*   ei  = (const int*)d_in[1];   // int32 (JAX x64 disabled canonicalizes int64)
  const float* W1  = (const float*)d_in[2];
  const float* as1 = (const float*)d_in[3];
  const float* ad1 = (const float*)d_in[4];
  const float* b1  = (const float*)d_in[5];
  const float* W2  = (const float*)d_in[6];
  const float* as2 = (const float*)d_in[7];
  const float* ad2 = (const float*)d_in[8];
  const float* b2  = (const float*)d_in[9];
  float* out = (float*)d_out;

  const int N = NNODE;
  const int E = in_sizes[1] / 2;

  char* base = (char*)d_ws;
  size_t off = 0;
  auto alloc = [&](size_t bytes) -> void* {
    void* p = base + off;
    off += (bytes + 255) & ~(size_t)255;
    return p;
  };
  u16*    hf16a  = (u16*)alloc((size_t)N * NC * 2);       // 25.6 MB layer-1 messages
  u16*    hf16b  = (u16*)alloc((size_t)N * NC * 2);       // 25.6 MB layer-2 messages (dbuf)
  u16*    h1bf   = (u16*)alloc((size_t)MPAD * HID * 2);   // 6.4 MB bf16 layer-1 out (padded)
  u16*    Bp1    = (u16*)alloc((size_t)FIN * NC * 2);     // packed W1
  u16*    Bp2    = (u16*)alloc((size_t)HID * NC * 2);     // packed W2
  float*  al_s1  = (float*)alloc((size_t)N * NH * 4);
  float*  al_d1  = (float*)alloc((size_t)N * NH * 4);
  float*  al_s2  = (float*)alloc((size_t)N * NH * 4);
  float*  al_d2  = (float*)alloc((size_t)N * NH * 4);
  int*    offs   = (int*)alloc((size_t)(N + 1) * 4);
  int*    rank   = (int*)alloc((size_t)E * 4);
  int*    csr    = (int*)alloc((size_t)E * 4);
  int*    bsums  = (int*)alloc(256 * 4);
  // deg + ready share one memset region (contiguous)
  int*    deg    = (int*)alloc((size_t)N * 4 + (size_t)(GEMMB + 64) * 4);
  int*    ready  = deg + N;

  const int edgeBlocks = (E + 255) / 256;       // 3125
  const int packBlocks = (FIN * NC + HID * NC + 255) / 256;  // 192

  // --- zero deg + ready in one memset; CSR build + weight pack ---
  hipMemsetAsync(deg, 0, (size_t)(N + GEMMB + 64) * 4, stream);
  count_pack<<<edgeBlocks + packBlocks, 256, 0, stream>>>(ei, deg, rank, E, edgeBlocks, W1, W2, Bp1, Bp2);
  scan_phase1<<<SCANB, 256, 0, stream>>>(deg, bsums, N);
  scan_phase23<<<SCANB, 256, 0, stream>>>(bsums, deg, offs, N);

  // --- layer-1 GEMM (MFMA) overlapped with edge scatter (independent) ---
  gemm1_scatter<<<GEMMB + edgeBlocks, 256, 0, stream>>>(
      x, Bp1, as1, ad1, hf16a, al_s1, al_d1, N,
      ei, offs, rank, csr, E, GEMMB);

  // --- layer-1 agg fused with layer-2 GEMM (per-tile readiness) ---
  agg1_gemm2<<<NODEB + GEMMB, 256, 0, stream>>>(
      hf16a, (const float4*)al_s1, (const float4*)al_d1, offs, csr, b1, h1bf, N,
      ready, Bp2, as2, ad2, hf16b, al_s2, al_d2, N);

  // --- layer-2 agg ---
  agg2_kernel<<<NODEB, 256, 0, stream>>>(hf16b, (const float4*)al_s2, (const float4*)al_d2,
                                         offs, csr, b2, out, N);
}